// Round 1
// baseline (421.277 us; speedup 1.0000x reference)
//
#include <hip/hip_runtime.h>
#include <stdint.h>

#define N_NODES 100000
#define N_EDGES 1600000
#define FDIM 128
#define NREL 50
#define BN_EPS 1e-3f
#define N_PAD 100096   // pad rows so GEMM tail tiles can read safely
#define SCAN_B 1024

typedef short short8_t __attribute__((ext_vector_type(8)));
typedef float f32x4_t __attribute__((ext_vector_type(4)));

__device__ __forceinline__ uint32_t f2bf(float f) {
    union { float f; uint32_t u; } v; v.f = f;
    uint32_t u = v.u;
    return (u + 0x7FFFu + ((u >> 16) & 1u)) >> 16;   // RNE, inputs finite
}
__device__ __forceinline__ float bflo(uint32_t p) {
    union { uint32_t u; float f; } v; v.u = p << 16; return v.f;
}
__device__ __forceinline__ float bfhi(uint32_t p) {
    union { uint32_t u; float f; } v; v.u = p & 0xFFFF0000u; return v.f;
}

// ---- prep: BN affine params, 1/(relc+1), W^T cast to bf16 ----
__global__ void prep_kernel(const float* __restrict__ gamma, const float* __restrict__ beta,
                            const float* __restrict__ mean, const float* __restrict__ var,
                            const float* __restrict__ relc, const float* __restrict__ W,
                            float* __restrict__ scale, float* __restrict__ shift,
                            float* __restrict__ rel_inv, uint16_t* __restrict__ WT) {
    int t = threadIdx.x;
    if (t < FDIM) {
        float s = gamma[t] * rsqrtf(var[t] + BN_EPS);
        scale[t] = s;
        shift[t] = beta[t] - mean[t] * s;
    }
    if (t < NREL) rel_inv[t] = 1.0f / (relc[t] + 1.0f);
    for (int idx = t; idx < FDIM * FDIM; idx += blockDim.x) {
        int f = idx >> 7, k = idx & 127;
        WT[idx] = (uint16_t)f2bf(W[k * FDIM + f]);   // WT[f][k]
    }
}

// ---- h = BN(x), stored bf16. One float4 (4 features) per thread. ----
__global__ void h_kernel(const float* __restrict__ x, const float* __restrict__ scale,
                         const float* __restrict__ shift, uint2* __restrict__ h) {
    int i4 = blockIdx.x * blockDim.x + threadIdx.x;      // 0 .. N*32-1
    if (i4 >= N_NODES * 32) return;
    int cg = (i4 & 31) * 4;
    float4 xv = ((const float4*)x)[i4];
    float4 sc = *(const float4*)(scale + cg);
    float4 sh = *(const float4*)(shift + cg);
    float h0 = xv.x * sc.x + sh.x;
    float h1 = xv.y * sc.y + sh.y;
    float h2 = xv.z * sc.z + sh.z;
    float h3 = xv.w * sc.w + sh.w;
    uint2 o;
    o.x = f2bf(h0) | (f2bf(h1) << 16);
    o.y = f2bf(h2) | (f2bf(h3) << 16);
    h[i4] = o;
}

// ---- CSR build ----
__global__ void hist_kernel(const int* __restrict__ rows, int* __restrict__ counts) {
    int e = blockIdx.x * blockDim.x + threadIdx.x;
    if (e < N_EDGES) atomicAdd(&counts[rows[e]], 1);
}

__global__ void scan1_kernel(const int* __restrict__ counts, int* __restrict__ bsum) {
    __shared__ int sm[SCAN_B];
    int t = threadIdx.x;
    int i = blockIdx.x * SCAN_B + t;
    sm[t] = (i < N_NODES) ? counts[i] : 0;
    __syncthreads();
    for (int s = SCAN_B / 2; s > 0; s >>= 1) {
        if (t < s) sm[t] += sm[t + s];
        __syncthreads();
    }
    if (t == 0) bsum[blockIdx.x] = sm[0];
}

__global__ void scan2_kernel(const int* __restrict__ bsum, int* __restrict__ boff, int nb) {
    if (threadIdx.x == 0) {
        int acc = 0;
        for (int b = 0; b < nb; ++b) { boff[b] = acc; acc += bsum[b]; }
    }
}

__global__ void scan3_kernel(const int* __restrict__ counts, const int* __restrict__ boff,
                             int* __restrict__ row_start, int* __restrict__ cursor) {
    __shared__ int sm[SCAN_B];
    int t = threadIdx.x;
    int i = blockIdx.x * SCAN_B + t;
    int v = (i < N_NODES) ? counts[i] : 0;
    sm[t] = v;
    __syncthreads();
    for (int off = 1; off < SCAN_B; off <<= 1) {
        int xv = 0;
        if (t >= off) xv = sm[t - off];
        __syncthreads();
        sm[t] += xv;
        __syncthreads();
    }
    if (i < N_NODES) {
        int ex = boff[blockIdx.x] + sm[t] - v;   // exclusive scan
        row_start[i] = ex;
        cursor[i] = ex;                          // scatter advances this to row_end
    }
}

__global__ void scatter_kernel(const int* __restrict__ rows, const int* __restrict__ cols,
                               const float* __restrict__ vals, const int* __restrict__ rels,
                               const float* __restrict__ rel_inv, int* __restrict__ cursor,
                               int* __restrict__ scol, float* __restrict__ sw) {
    int e = blockIdx.x * blockDim.x + threadIdx.x;
    if (e < N_EDGES) {
        int r = rows[e];
        int p = atomicAdd(&cursor[r], 1);
        scol[p] = cols[e];
        sw[p] = vals[e] * rel_inv[rels[e]];
    }
}

// ---- pull-mode SpMM + diag term: pre[i] = sum_e w_e h[col_e] + (ck_i+1) h[i] (bf16 out) ----
__global__ __launch_bounds__(256) void spmm_kernel(
        const uint32_t* __restrict__ h, const int* __restrict__ row_start,
        const int* __restrict__ row_end, const int* __restrict__ scol,
        const float* __restrict__ sw, const float* __restrict__ ck,
        uint32_t* __restrict__ pre) {
    int row = blockIdx.x * 4 + (threadIdx.x >> 6);
    int lane = threadIdx.x & 63;
    uint32_t p = h[(size_t)row * 64 + lane];
    float coef = ck[row] + 1.0f;
    float ax = coef * bflo(p);
    float ay = coef * bfhi(p);
    int e0 = row_start[row], e1 = row_end[row];
    for (int base = e0; base < e1; base += 64) {
        int cnt = min(64, e1 - base);
        int myc = 0; float myw = 0.f;
        if (lane < cnt) { myc = scol[base + lane]; myw = sw[base + lane]; }
        int i = 0;
        for (; i + 4 <= cnt; i += 4) {
            int c0 = __shfl(myc, i), c1 = __shfl(myc, i + 1);
            int c2 = __shfl(myc, i + 2), c3 = __shfl(myc, i + 3);
            float w0 = __shfl(myw, i), w1 = __shfl(myw, i + 1);
            float w2 = __shfl(myw, i + 2), w3 = __shfl(myw, i + 3);
            uint32_t q0 = h[(size_t)c0 * 64 + lane];
            uint32_t q1 = h[(size_t)c1 * 64 + lane];
            uint32_t q2 = h[(size_t)c2 * 64 + lane];
            uint32_t q3 = h[(size_t)c3 * 64 + lane];
            ax += w0 * bflo(q0); ay += w0 * bfhi(q0);
            ax += w1 * bflo(q1); ay += w1 * bfhi(q1);
            ax += w2 * bflo(q2); ay += w2 * bfhi(q2);
            ax += w3 * bflo(q3); ay += w3 * bfhi(q3);
        }
        for (; i < cnt; ++i) {
            int c = __shfl(myc, i);
            float wv = __shfl(myw, i);
            uint32_t q = h[(size_t)c * 64 + lane];
            ax += wv * bflo(q); ay += wv * bfhi(q);
        }
    }
    pre[(size_t)row * 64 + lane] = f2bf(ax) | (f2bf(ay) << 16);
}

// ---- out = pre @ W + bias via MFMA bf16 16x16x32.
// A frag: m=lane&15, k = 32*t + (lane>>4)*8 + j  (8 contiguous bf16 in row-major pre)
// B frag: n=lane&15, same k pattern (contiguous in WT[f][k])
// D frag: col = lane&15, row = (lane>>4)*4 + r  [verified layout]
__global__ __launch_bounds__(256) void gemm_kernel(
        const uint16_t* __restrict__ pre, const uint16_t* __restrict__ WT,
        const float* __restrict__ bias, float* __restrict__ out) {
    int wave = threadIdx.x >> 6;
    int lane = threadIdx.x & 63;
    int row0 = blockIdx.x * 64 + wave * 16;
    int m = lane & 15, q = lane >> 4;

    short8_t a[4];
    const uint16_t* arow = pre + (size_t)(row0 + m) * FDIM + q * 8;
#pragma unroll
    for (int t = 0; t < 4; ++t)
        a[t] = *(const short8_t*)(arow + t * 32);

    for (int ct = 0; ct < 8; ++ct) {
        int col0 = ct * 16;
        const uint16_t* brow = WT + (size_t)(col0 + m) * FDIM + q * 8;
        f32x4_t acc = {0.f, 0.f, 0.f, 0.f};
#pragma unroll
        for (int t = 0; t < 4; ++t) {
            short8_t b = *(const short8_t*)(brow + t * 32);
            acc = __builtin_amdgcn_mfma_f32_16x16x32_bf16(a[t], b, acc, 0, 0, 0);
        }
        float bs = bias[col0 + m];
#pragma unroll
        for (int r = 0; r < 4; ++r) {
            int row = row0 + q * 4 + r;
            if (row < N_NODES)
                out[(size_t)row * FDIM + col0 + m] = acc[r] + bs;
        }
    }
}

extern "C" void kernel_launch(void* const* d_in, const int* in_sizes, int n_in,
                              void* d_out, int out_size, void* d_ws, size_t ws_size,
                              hipStream_t stream) {
    const float* x     = (const float*)d_in[0];
    const int*   erows = (const int*)d_in[1];
    const int*   ecols = (const int*)d_in[2];
    const float* evals = (const float*)d_in[3];
    const int*   erels = (const int*)d_in[4];
    const float* relc  = (const float*)d_in[5];
    const float* ck    = (const float*)d_in[6];
    const float* W     = (const float*)d_in[7];
    const float* bias  = (const float*)d_in[8];
    const float* gamma = (const float*)d_in[9];
    const float* beta  = (const float*)d_in[10];
    const float* mean  = (const float*)d_in[11];
    const float* var   = (const float*)d_in[12];
    float* out = (float*)d_out;

    char* wp = (char*)d_ws;
    auto alloc = [&](size_t bytes) {
        char* p = wp;
        wp += (bytes + 255) & ~(size_t)255;
        return (void*)p;
    };
    uint16_t* h      = (uint16_t*)alloc((size_t)N_PAD * FDIM * 2);
    uint16_t* pre    = (uint16_t*)alloc((size_t)N_PAD * FDIM * 2);
    int*   scol      = (int*)alloc((size_t)N_EDGES * 4);
    float* sw        = (float*)alloc((size_t)N_EDGES * 4);
    int* counts      = (int*)alloc((size_t)N_NODES * 4);
    int* row_start   = (int*)alloc((size_t)N_NODES * 4);
    int* cursor      = (int*)alloc((size_t)N_NODES * 4);
    int* bsum        = (int*)alloc(1024 * 4);
    int* boff        = (int*)alloc(1024 * 4);
    uint16_t* WT     = (uint16_t*)alloc(FDIM * FDIM * 2);
    float* scale     = (float*)alloc(FDIM * 4);
    float* shift     = (float*)alloc(FDIM * 4);
    float* rel_inv   = (float*)alloc(256 * 4);
    if ((size_t)(wp - (char*)d_ws) > ws_size) return;   // fail loudly via validation, not OOB

    hipMemsetAsync(counts, 0, (size_t)N_NODES * 4, stream);
    prep_kernel<<<1, 256, 0, stream>>>(gamma, beta, mean, var, relc, W, scale, shift, rel_inv, WT);
    h_kernel<<<(N_NODES * 32) / 256, 256, 0, stream>>>(x, scale, shift, (uint2*)h);
    hist_kernel<<<(N_EDGES + 255) / 256, 256, 0, stream>>>(erows, counts);
    int nb = (N_NODES + SCAN_B - 1) / SCAN_B;
    scan1_kernel<<<nb, SCAN_B, 0, stream>>>(counts, bsum);
    scan2_kernel<<<1, 64, 0, stream>>>(bsum, boff, nb);
    scan3_kernel<<<nb, SCAN_B, 0, stream>>>(counts, boff, row_start, cursor);
    scatter_kernel<<<(N_EDGES + 255) / 256, 256, 0, stream>>>(erows, ecols, evals, erels,
                                                              rel_inv, cursor, scol, sw);
    spmm_kernel<<<N_NODES / 4, 256, 0, stream>>>((const uint32_t*)h, row_start, cursor,
                                                 scol, sw, ck, (uint32_t*)pre);
    gemm_kernel<<<(N_NODES + 63) / 64, 256, 0, stream>>>(pre, WT, bias, out);
}